// Round 1
// baseline (641.521 us; speedup 1.0000x reference)
//
#include <hip/hip_runtime.h>
#include <hip/hip_bf16.h>

#define T_SEQ 256
#define BATCH 1024

typedef __attribute__((ext_vector_type(8))) short  short8;   // 8 bf16 (x32 MFMA frag)
typedef __attribute__((ext_vector_type(4))) short  short4v;  // 4 bf16 (x16 MFMA frag)
typedef __attribute__((ext_vector_type(4))) float  floatx4;  // MFMA C/D frag
typedef unsigned short ushort_t;
typedef unsigned int   uint_t;

template <int P> struct IC { static constexpr int v = P; };

constexpr float NL2E = -1.4426950408889634f;   // -log2(e): sigmoid = rcp(1+exp2(z))
constexpr float L2E2 =  2.8853900817779268f;   // 2*log2(e): tanh = 1-2*rcp(1+exp2(x))

__device__ __forceinline__ float exp2_fast(float x) {
    float r; asm("v_exp_f32 %0, %1" : "=v"(r) : "v"(x)); return r;
}
__device__ __forceinline__ float rcp_fast(float x) {
    float r; asm("v_rcp_f32 %0, %1" : "=v"(r) : "v"(x)); return r;
}
__device__ __forceinline__ ushort_t f2bf(float f) {
    union { float f; uint_t u; } v; v.f = f;
    uint_t r = v.u + 0x7FFFu + ((v.u >> 16) & 1u);   // RNE
    return (ushort_t)(r >> 16);
}
__device__ __forceinline__ uint_t pk_bf16(float a, float b) {
    union { __hip_bfloat162 h; uint_t u; } v;
    v.h = __float22bfloat162_rn(make_float2(a, b));
    return v.u;
}
// Barrier WITHOUT vmcnt drain: LDS ordering only; global loads/stores stay in flight.
__device__ __forceinline__ void sync_lds() {
    asm volatile("s_waitcnt lgkmcnt(0)\n\ts_barrier" ::: "memory");
}
// 16x16x16 bf16 MFMA (K=16): ISA-listed on gfx950 (cdna4_isa.md §10). Used for the
// register-resident h path: its B-frag (k=(lane>>4)*4+e, n=lane&15) is EXACTLY the
// cvt_pk-packed C' output of the swapped-layout step — zero cross-lane traffic.
__device__ __forceinline__ floatx4 mfma16(short4v a, short4v b, floatx4 c) {
#if __has_builtin(__builtin_amdgcn_mfma_f32_16x16x16bf16_1k)
    return __builtin_amdgcn_mfma_f32_16x16x16bf16_1k(a, b, c, 0, 0, 0);
#else
    floatx4 d;
    asm("v_mfma_f32_16x16x16_bf16 %0, %1, %2, %3" : "=v"(d) : "v"(a), "v"(b), "v"(c));
    return d;
#endif
}

// Fused persistent LSTM layer, SWAPPED layout: we compute z^T = [W;U]^T · in^T via
// mfma(A=weight-frag, B=input-frag). A/B frag maps are identical (m<->n), so weight
// prepack and x loads are byte-identical to the classic layout; only the C' map flips:
//   C'[m=unit][n=row]: lane holds row = lane&15, units = tilebase + (lane>>4)*4 + reg.
// => each lane's 4 h outputs are 4 CONSECUTIVE units of one row: 2 cvt_pk give the
// bf16 pair-dwords directly usable as (a) one ds_write_b64 (LDS path, L1), or
// (b) the 16x16x16 h-MFMA B-frag itself (REGH path, L2/L3: NO LDS, NO barrier).
//  - REGH: one wave owns all H units; h lives in registers across steps (hfrag).
//  - !REGH: H/16 waves; h ping-pongs in LDS ([row][unit], b64 write / b128 read),
//    one lgkm-only barrier per step.
//  - bias rides as the C operand of the first x-MFMA (no acc-init movs).
//  - cst holds 2log2e*c (prescaled) to shave one mul off the c->tanh chain.
//  - x A..B-frags prefetched 4 steps deep in a register ring (fp32->bf16 packed conv
//    for layer 1); 4-phase unroll => distinct store-data regs, vmcnt looks 4 back.
template <int D, int H, bool IS_FIRST, bool SEQ_OUT, bool REGH>
__global__ __launch_bounds__(REGH ? 64 : 64 * (H / 16), 1) void lstm_fused(
    const void* __restrict__ xin,
    const float* __restrict__ Wf, const float* __restrict__ Uf, const float* __restrict__ bgf,
    const float* __restrict__ Wb, const float* __restrict__ Ub, const float* __restrict__ bgb,
    void* __restrict__ outp)
{
    constexpr int UG  = REGH ? 1 : H / 16;       // waves per block
    constexpr int NT  = REGH ? H / 16 : 1;       // m-tiles (16 units) per wave per gate
    constexpr int KSx = D / 32;                  // x k-chunks (16x16x32)
    constexpr int KSh = REGH ? 1 : H / 32;       // LDS-h k-chunks (dummy 1 when REGH)
    constexpr int NC  = REGH ? H / 16 : 1;       // register-h k-chunks (16x16x16)
    constexpr int HP  = (H < 32 ? 32 : H) + 8;   // padded h row stride (u16)
    constexpr int G4  = 4 * H;
    constexpr int NTH = 64 * UG;
    static_assert(D % 32 == 0 && T_SEQ % 4 == 0, "shape");

    const int tid  = threadIdx.x;
    const int ug   = tid >> 6;
    const int lane = tid & 63;
    const int lm   = lane & 15;
    const int lq   = lane >> 4;
    const int dir  = blockIdx.y;
    const int b0   = blockIdx.x * 16;

    const float* W  = dir ? Wb  : Wf;
    const float* U  = dir ? Ub  : Uf;
    const float* bg = dir ? bgb : bgf;

    __shared__ __align__(16) ushort_t hbuf[REGH ? 8 : 2 * 16 * HP];

    // ---- one-time weight prepack (pre-scaled by -log2e / 2log2e) ----
    short8  aw[4][NT][KSx];   // W^T x32 A-frags
    short8  hw[4][NT][KSh];   // U^T x32 A-frags (LDS path)
    short4v uw[4][NT][NC];    // U^T x16 A-frags (REGH path)
    floatx4 bias4[4][NT];     // bias per C'-reg (unit = base + lq*4 + r)
#pragma unroll
    for (int g = 0; g < 4; g++) {
        const float sc = (g == 2) ? L2E2 : NL2E;
#pragma unroll
        for (int t = 0; t < NT; t++) {
            const int ub = g * H + (REGH ? t * 16 : ug * 16);
            floatx4 b4;
#pragma unroll
            for (int r = 0; r < 4; r++) b4[r] = sc * bg[ub + lq * 4 + r];
            bias4[g][t] = b4;
            const int nc = ub + lm;                      // unit column (m = lane&15)
#pragma unroll
            for (int ks = 0; ks < KSx; ks++) {
                short8 f;
#pragma unroll
                for (int e = 0; e < 8; e++)
                    f[e] = (short)f2bf(sc * W[(ks * 32 + lq * 8 + e) * G4 + nc]);
                aw[g][t][ks] = f;
            }
            if constexpr (!REGH) {
#pragma unroll
                for (int ks = 0; ks < KSh; ks++) {
                    short8 f;
#pragma unroll
                    for (int e = 0; e < 8; e++) {
                        const int k = ks * 32 + lq * 8 + e;
                        f[e] = (k < H) ? (short)f2bf(sc * U[k * G4 + nc]) : (short)0;
                    }
                    hw[g][t][ks] = f;
                }
            } else {
#pragma unroll
                for (int c = 0; c < NC; c++) {
                    short4v f;
#pragma unroll
                    for (int e = 0; e < 4; e++)
                        f[e] = (short)f2bf(sc * U[(c * 16 + lq * 4 + e) * G4 + nc]);
                    uw[g][t][c] = f;
                }
            }
        }
    }

    if constexpr (!REGH) {
        for (int idx = tid; idx < 2 * 16 * HP; idx += NTH)
            hbuf[idx] = 0;   // h0 = 0
    }

    float   cst[NT][4];      // holds 2log2e * c
    float   hl[NT][4];
    short4v hfrag[NC];       // REGH: previous-step h, already in B-frag form
#pragma unroll
    for (int t = 0; t < NT; t++)
#pragma unroll
        for (int r = 0; r < 4; r++) { cst[t][r] = 0.f; hl[t][r] = 0.f; }
    if constexpr (REGH) {
#pragma unroll
        for (int c = 0; c < NC; c++) hfrag[c] = (short4v){0, 0, 0, 0};
    }

    const int t0 = dir ? T_SEQ - 1 : 0;
    // stepping pointers (no per-step 64-bit muls); loads identical to classic layout
    const float*    pxf = (const float*)xin + ((size_t)(b0 + lm) * T_SEQ + t0) * D + lq * 8;
    const ushort_t* pxb = (const ushort_t*)xin + ((size_t)t0 * BATCH + b0 + lm) * D + lq * 8;
    const long xstepf = dir ? -(long)D : (long)D;
    const long xstepb = (dir ? -(long)BATCH : (long)BATCH) * D;
    ushort_t* pout = (ushort_t*)outp +
        ((size_t)t0 * BATCH + b0 + lm) * (2 * H) + dir * H + (REGH ? 0 : ug * 16) + lq * 4;
    const long ostep = (dir ? -(long)BATCH : (long)BATCH) * (2 * H);

    // x prefetch ring, depth 4
    float4 rawf[4][2 * KSx];   // layer-1 path (fp32 input); DCE'd otherwise
    short8 rawb[4][KSx];       // bf16 path

    auto load_slot = [&](auto sl_) {
        constexpr int SL = decltype(sl_)::v;
        if (IS_FIRST) {
#pragma unroll
            for (int ks = 0; ks < KSx; ks++) {
                rawf[SL][2 * ks + 0] = *(const float4*)(pxf + ks * 32 + 0);
                rawf[SL][2 * ks + 1] = *(const float4*)(pxf + ks * 32 + 4);
            }
            pxf += xstepf;
        } else {
#pragma unroll
            for (int ks = 0; ks < KSx; ks++)
                rawb[SL][ks] = *(const short8*)(pxb + ks * 32);
            pxb += xstepb;
        }
    };

    load_slot(IC<0>{}); load_slot(IC<1>{}); load_slot(IC<2>{}); load_slot(IC<3>{});
    if constexpr (!REGH) __syncthreads();   // hbuf zeros visible

    auto step = [&](auto p_, auto sl_, int s) {
        constexpr int P  = decltype(p_)::v;
        constexpr int SL = decltype(sl_)::v;

        // h B-frags from LDS (issued first; x-MFMAs overlap the lgkm latency)
        short8 fh[KSh];
        if constexpr (!REGH) {
#pragma unroll
            for (int ks = 0; ks < KSh; ks++)
                fh[ks] = *(const short8*)&hbuf[(P * 16 + lm) * HP + ks * 32 + lq * 8];
        }

        // x B-frags from the register ring (packed fp32->bf16 conv on layer 1)
        short8 av[KSx];
        if (IS_FIRST) {
#pragma unroll
            for (int ks = 0; ks < KSx; ks++) {
                union { short8 s; uint_t u[4]; } f;
                const float* ra = (const float*)&rawf[SL][2 * ks];
#pragma unroll
                for (int e = 0; e < 4; e++) f.u[e] = pk_bf16(ra[2 * e], ra[2 * e + 1]);
                av[ks] = f.s;
            }
        } else {
#pragma unroll
            for (int ks = 0; ks < KSx; ks++) av[ks] = rawb[SL][ks];
        }

        floatx4 acc[4][NT];
        // first x-MFMA carries the bias as C (no acc-init movs)
#pragma unroll
        for (int g = 0; g < 4; g++)
#pragma unroll
            for (int t = 0; t < NT; t++)
                acc[g][t] = __builtin_amdgcn_mfma_f32_16x16x32_bf16(aw[g][t][0], av[0], bias4[g][t], 0, 0, 0);
#pragma unroll
        for (int ks = 1; ks < KSx; ks++)
#pragma unroll
            for (int g = 0; g < 4; g++)
#pragma unroll
                for (int t = 0; t < NT; t++)
                    acc[g][t] = __builtin_amdgcn_mfma_f32_16x16x32_bf16(aw[g][t][ks], av[ks], acc[g][t], 0, 0, 0);

        if (s + 4 < T_SEQ) load_slot(sl_);   // refill consumed slot (uniform branch)

        // recurrent part last (shortest possible h -> MFMA distance)
        if constexpr (!REGH) {
#pragma unroll
            for (int ks = 0; ks < KSh; ks++)
#pragma unroll
                for (int g = 0; g < 4; g++)
                    acc[g][0] = __builtin_amdgcn_mfma_f32_16x16x32_bf16(hw[g][0][ks], fh[ks], acc[g][0], 0, 0, 0);
        } else {
#pragma unroll
            for (int c = 0; c < NC; c++)
#pragma unroll
                for (int g = 0; g < 4; g++)
#pragma unroll
                    for (int t = 0; t < NT; t++)
                        acc[g][t] = mfma16(uw[g][t][c], hfrag[c], acc[g][t]);
        }

        // gates + c/h update, pure-register (pre-scaled z; cst = 2log2e*c)
#pragma unroll
        for (int t = 0; t < NT; t++) {
            float hv[4];
#pragma unroll
            for (int r = 0; r < 4; r++) {
                const float gi = rcp_fast(1.0f + exp2_fast(acc[0][t][r]));
                const float gf = rcp_fast(1.0f + exp2_fast(acc[1][t][r]));
                const float gg = 1.0f - 2.0f * rcp_fast(1.0f + exp2_fast(acc[2][t][r]));
                const float go = rcp_fast(1.0f + exp2_fast(acc[3][t][r]));
                cst[t][r] = fmaf(gf, cst[t][r], L2E2 * (gi * gg));
                const float tc = 1.0f - 2.0f * rcp_fast(1.0f + exp2_fast(cst[t][r]));
                hv[r] = go * tc;
            }
            const uint_t d0 = pk_bf16(hv[0], hv[1]);   // units +0,+1
            const uint_t d1 = pk_bf16(hv[2], hv[3]);   // units +2,+3
            if constexpr (REGH) {
                union { uint_t u[2]; short4v s; } pp;
                pp.u[0] = d0; pp.u[1] = d1;
                hfrag[t] = pp.s;                        // next step's h B-frag, in-register
            } else {
                uint2 wv; wv.x = d0; wv.y = d1;
                *(uint2*)&hbuf[((P ^ 1) * 16 + lm) * HP + ug * 16 + lq * 4] = wv;   // 1x b64
            }
            if (SEQ_OUT) {
                uint2 ov; ov.x = d0; ov.y = d1;
                *(uint2*)&pout[t * 16] = ov;            // 1x dwordx2 (was 4x b16)
            } else {
#pragma unroll
                for (int r = 0; r < 4; r++) hl[t][r] = hv[r];
            }
        }
        pout += ostep;
        if (UG > 1) sync_lds();   // lgkm-only; REGH/single-wave layers need no barrier
    };

    for (int s = 0; s < T_SEQ; s += 4) {
        step(IC<0>{}, IC<0>{}, s);
        step(IC<1>{}, IC<1>{}, s + 1);
        step(IC<0>{}, IC<2>{}, s + 2);
        step(IC<1>{}, IC<3>{}, s + 3);
    }

    if (!SEQ_OUT) {
        float* op = (float*)outp;
#pragma unroll
        for (int t = 0; t < NT; t++) {
            float4 v4 = make_float4(hl[t][0], hl[t][1], hl[t][2], hl[t][3]);
            *(float4*)&op[(size_t)(b0 + lm) * (2 * H) + dir * H + (REGH ? t * 16 : ug * 16) + lq * 4] = v4;
        }
    }
}

// Dense head: relu6(x@Wd1+bd1) @ Wd2 + bd2 -> softmax(2). One row per thread.
__global__ __launch_bounds__(256) void dense_head(
    const float* __restrict__ h3, const float* __restrict__ Wd1, const float* __restrict__ bd1,
    const float* __restrict__ Wd2, const float* __restrict__ bd2, float* __restrict__ out)
{
    const int b = blockIdx.x * blockDim.x + threadIdx.x;
    if (b >= BATCH) return;
    float x[32];
#pragma unroll
    for (int k = 0; k < 32; k++) x[k] = h3[b * 32 + k];
    float y[16];
#pragma unroll
    for (int jj = 0; jj < 16; jj++) {
        float a = bd1[jj];
#pragma unroll
        for (int k = 0; k < 32; k++) a = fmaf(x[k], Wd1[k * 16 + jj], a);
        y[jj] = fminf(fmaxf(a, 0.0f), 6.0f);
    }
    float l0 = bd2[0], l1 = bd2[1];
#pragma unroll
    for (int k = 0; k < 16; k++) {
        l0 = fmaf(y[k], Wd2[k * 2 + 0], l0);
        l1 = fmaf(y[k], Wd2[k * 2 + 1], l1);
    }
    const float m = fmaxf(l0, l1);
    const float e0 = __expf(l0 - m), e1 = __expf(l1 - m);
    const float inv = 1.0f / (e0 + e1);
    out[b * 2 + 0] = e0 * inv;
    out[b * 2 + 1] = e1 * inv;
}

extern "C" void kernel_launch(void* const* d_in, const int* in_sizes, int n_in,
                              void* d_out, int out_size, void* d_ws, size_t ws_size,
                              hipStream_t stream)
{
    const float* x   = (const float*)d_in[0];
    const float* W1f = (const float*)d_in[1];
    const float* U1f = (const float*)d_in[2];
    const float* b1f = (const float*)d_in[3];
    const float* W1b = (const float*)d_in[4];
    const float* U1b = (const float*)d_in[5];
    const float* b1b = (const float*)d_in[6];
    const float* W2f = (const float*)d_in[7];
    const float* U2f = (const float*)d_in[8];
    const float* b2f = (const float*)d_in[9];
    const float* W2b = (const float*)d_in[10];
    const float* U2b = (const float*)d_in[11];
    const float* b2b = (const float*)d_in[12];
    const float* W3f = (const float*)d_in[13];
    const float* U3f = (const float*)d_in[14];
    const float* b3f = (const float*)d_in[15];
    const float* W3b = (const float*)d_in[16];
    const float* U3b = (const float*)d_in[17];
    const float* b3b = (const float*)d_in[18];
    const float* Wd1 = (const float*)d_in[19];
    const float* bd1 = (const float*)d_in[20];
    const float* Wd2 = (const float*)d_in[21];
    const float* bd2 = (const float*)d_in[22];

    // workspace: 96 MB + 128 KB footprint
    char* ws = (char*)d_ws;
    void*  l1out = (void*)ws;                                  // [T][B][128] bf16 = 64 MB
    void*  l2out = (void*)(ws + (size_t)64 * 1024 * 1024);     // [T][B][64]  bf16 = 32 MB
    float* h3    = (float*)(ws + (size_t)96 * 1024 * 1024);    // [B][32] fp32 = 128 KB
    float* out   = (float*)d_out;

    dim3 grid(BATCH / 16, 2);

    lstm_fused<64, 64, true, true, false>     // 4 waves/block, LDS h exchange
        <<<grid, 256, 0, stream>>>(x, W1f, U1f, b1f, W1b, U1b, b1b, l1out);
    lstm_fused<128, 32, false, true, true>    // 1 wave, register-resident h
        <<<grid, 64, 0, stream>>>(l1out, W2f, U2f, b2f, W2b, U2b, b2b, l2out);
    lstm_fused<64, 16, false, false, true>    // 1 wave, register-resident h
        <<<grid, 64, 0, stream>>>(l2out, W3f, U3f, b3f, W3b, U3b, b3b, h3);
    dense_head<<<dim3(BATCH / 256), 256, 0, stream>>>(h3, Wd1, bd1, Wd2, bd2, out);
}

// Round 2
// 527.839 us; speedup vs baseline: 1.2154x; 1.2154x over previous
//
#include <hip/hip_runtime.h>
#include <hip/hip_bf16.h>

#define T_SEQ 256
#define BATCH 1024

typedef __attribute__((ext_vector_type(8))) short  short8;   // 8 bf16 (x32 MFMA frag)
typedef __attribute__((ext_vector_type(4))) short  short4v;  // 4 bf16 (x16 MFMA frag)
typedef __attribute__((ext_vector_type(4))) float  floatx4;  // MFMA C/D frag
typedef unsigned short ushort_t;
typedef unsigned int   uint_t;

template <int P> struct IC { static constexpr int v = P; };

constexpr float NL2E = -1.4426950408889634f;   // -log2(e): sigmoid = rcp(1+exp2(z))
constexpr float L2E2 =  2.8853900817779268f;   // 2*log2(e): tanh = 1-2*rcp(1+exp2(x))

__device__ __forceinline__ float exp2_fast(float x) {
    float r; asm("v_exp_f32 %0, %1" : "=v"(r) : "v"(x)); return r;
}
__device__ __forceinline__ float rcp_fast(float x) {
    float r; asm("v_rcp_f32 %0, %1" : "=v"(r) : "v"(x)); return r;
}
__device__ __forceinline__ ushort_t f2bf(float f) {
    union { float f; uint_t u; } v; v.f = f;
    uint_t r = v.u + 0x7FFFu + ((v.u >> 16) & 1u);   // RNE
    return (ushort_t)(r >> 16);
}
__device__ __forceinline__ uint_t pk_bf16(float a, float b) {
    union { __hip_bfloat162 h; uint_t u; } v;
    v.h = __float22bfloat162_rn(make_float2(a, b));
    return v.u;
}
// Barrier WITHOUT vmcnt drain: LDS ordering only; global loads/stores stay in flight.
__device__ __forceinline__ void sync_lds() {
    asm volatile("s_waitcnt lgkmcnt(0)\n\ts_barrier" ::: "memory");
}
// 16x16x16 bf16 MFMA (K=16): used only on the REGH path where (D+H) weight frags fit
// in VGPRs. Its B-frag (k=(lane>>4)*4+e, n=lane&15) is exactly the cvt_pk-packed C'
// output of the swapped-layout step — zero cross-lane traffic for the recurrence.
__device__ __forceinline__ floatx4 mfma16(short4v a, short4v b, floatx4 c) {
#if __has_builtin(__builtin_amdgcn_mfma_f32_16x16x16bf16_1k)
    return __builtin_amdgcn_mfma_f32_16x16x16bf16_1k(a, b, c, 0, 0, 0);
#else
    floatx4 d;
    asm("v_mfma_f32_16x16x16_bf16 %0, %1, %2, %3" : "=v"(d) : "v"(a), "v"(b), "v"(c));
    return d;
#endif
}

// Fused persistent LSTM layer, SWAPPED layout: z^T = [W;U]^T · in^T via
// mfma(A=weight-frag, B=input-frag). A/B frag maps are identical (m<->n), so weight
// prepack and x loads are byte-identical to the classic layout; only the C' map flips:
//   C'[m=unit][n=row]: lane holds row = lane&15, units = tilebase + (lane>>4)*4 + reg.
// => each lane's 4 h outputs are 4 CONSECUTIVE units of one row: 2 cvt_pk give the
// bf16 pair-dwords directly usable as (a) one ds_write_b64 (LDS path), or
// (b) the 16x16x16 h-MFMA B-frag itself (REGH path: NO LDS, NO barrier).
//  - REGH (VGPR-gated: needs (D+H)*4H*2B/64 + ring + acc < 256 VGPR => L3 only):
//    one wave owns all H units; h lives in registers across steps (hfrag).
//    R1 post-mortem: REGH at D=128/H=32 needs ~300 VGPR -> 188 allocated + spills
//    -> 231 us (was 160). NEVER enable REGH unless the weight frags fit.
//  - !REGH: H/16 waves; h ping-pongs in LDS ([row][unit], b64 write / b128 read),
//    one lgkm-only barrier per step.
//  - bias rides as the C operand of the first x-MFMA (no acc-init movs).
//  - cst holds 2log2e*c (prescaled) to shave one mul off the c->tanh chain.
//  - x B-frags prefetched 4 steps deep in a register ring (fp32->bf16 packed conv
//    for layer 1); 4-phase unroll => distinct store-data regs, vmcnt looks 4 back.
template <int D, int H, bool IS_FIRST, bool SEQ_OUT, bool REGH>
__global__ __launch_bounds__(REGH ? 64 : 64 * (H / 16), 1) void lstm_fused(
    const void* __restrict__ xin,
    const float* __restrict__ Wf, const float* __restrict__ Uf, const float* __restrict__ bgf,
    const float* __restrict__ Wb, const float* __restrict__ Ub, const float* __restrict__ bgb,
    void* __restrict__ outp)
{
    constexpr int UG  = REGH ? 1 : H / 16;       // waves per block
    constexpr int NT  = REGH ? H / 16 : 1;       // m-tiles (16 units) per wave per gate
    constexpr int KSx = D / 32;                  // x k-chunks (16x16x32)
    constexpr int KSh = REGH ? 1 : H / 32;       // LDS-h k-chunks (dummy 1 when REGH)
    constexpr int NC  = REGH ? H / 16 : 1;       // register-h k-chunks (16x16x16)
    constexpr int HP  = (H < 32 ? 32 : H) + 8;   // padded h row stride (u16)
    constexpr int G4  = 4 * H;
    constexpr int NTH = 64 * UG;
    static_assert(D % 32 == 0 && T_SEQ % 4 == 0, "shape");

    const int tid  = threadIdx.x;
    const int ug   = tid >> 6;
    const int lane = tid & 63;
    const int lm   = lane & 15;
    const int lq   = lane >> 4;
    const int dir  = blockIdx.y;
    const int b0   = blockIdx.x * 16;

    const float* W  = dir ? Wb  : Wf;
    const float* U  = dir ? Ub  : Uf;
    const float* bg = dir ? bgb : bgf;

    __shared__ __align__(16) ushort_t hbuf[REGH ? 8 : 2 * 16 * HP];

    // ---- one-time weight prepack (pre-scaled by -log2e / 2log2e) ----
    short8  aw[4][NT][KSx];   // W^T x32 A-frags
    short8  hw[4][NT][KSh];   // U^T x32 A-frags (LDS path)
    short4v uw[4][NT][NC];    // U^T x16 A-frags (REGH path)
    floatx4 bias4[4][NT];     // bias per C'-reg (unit = base + lq*4 + r)
#pragma unroll
    for (int g = 0; g < 4; g++) {
        const float sc = (g == 2) ? L2E2 : NL2E;
#pragma unroll
        for (int t = 0; t < NT; t++) {
            const int ub = g * H + (REGH ? t * 16 : ug * 16);
            floatx4 b4;
#pragma unroll
            for (int r = 0; r < 4; r++) b4[r] = sc * bg[ub + lq * 4 + r];
            bias4[g][t] = b4;
            const int nc = ub + lm;                      // unit column (m = lane&15)
#pragma unroll
            for (int ks = 0; ks < KSx; ks++) {
                short8 f;
#pragma unroll
                for (int e = 0; e < 8; e++)
                    f[e] = (short)f2bf(sc * W[(ks * 32 + lq * 8 + e) * G4 + nc]);
                aw[g][t][ks] = f;
            }
            if constexpr (!REGH) {
#pragma unroll
                for (int ks = 0; ks < KSh; ks++) {
                    short8 f;
#pragma unroll
                    for (int e = 0; e < 8; e++) {
                        const int k = ks * 32 + lq * 8 + e;
                        f[e] = (k < H) ? (short)f2bf(sc * U[k * G4 + nc]) : (short)0;
                    }
                    hw[g][t][ks] = f;
                }
            } else {
#pragma unroll
                for (int c = 0; c < NC; c++) {
                    short4v f;
#pragma unroll
                    for (int e = 0; e < 4; e++)
                        f[e] = (short)f2bf(sc * U[(c * 16 + lq * 4 + e) * G4 + nc]);
                    uw[g][t][c] = f;
                }
            }
        }
    }

    if constexpr (!REGH) {
        for (int idx = tid; idx < 2 * 16 * HP; idx += NTH)
            hbuf[idx] = 0;   // h0 = 0
    }

    float   cst[NT][4];      // holds 2log2e * c
    float   hl[NT][4];
    short4v hfrag[NC];       // REGH: previous-step h, already in B-frag form
#pragma unroll
    for (int t = 0; t < NT; t++)
#pragma unroll
        for (int r = 0; r < 4; r++) { cst[t][r] = 0.f; hl[t][r] = 0.f; }
    if constexpr (REGH) {
#pragma unroll
        for (int c = 0; c < NC; c++) hfrag[c] = (short4v){0, 0, 0, 0};
    }

    const int t0 = dir ? T_SEQ - 1 : 0;
    // stepping pointers (no per-step 64-bit muls); loads identical to classic layout
    const float*    pxf = (const float*)xin + ((size_t)(b0 + lm) * T_SEQ + t0) * D + lq * 8;
    const ushort_t* pxb = (const ushort_t*)xin + ((size_t)t0 * BATCH + b0 + lm) * D + lq * 8;
    const long xstepf = dir ? -(long)D : (long)D;
    const long xstepb = (dir ? -(long)BATCH : (long)BATCH) * D;
    ushort_t* pout = (ushort_t*)outp +
        ((size_t)t0 * BATCH + b0 + lm) * (2 * H) + dir * H + (REGH ? 0 : ug * 16) + lq * 4;
    const long ostep = (dir ? -(long)BATCH : (long)BATCH) * (2 * H);

    // x prefetch ring, depth 4
    float4 rawf[4][2 * KSx];   // layer-1 path (fp32 input); DCE'd otherwise
    short8 rawb[4][KSx];       // bf16 path

    auto load_slot = [&](auto sl_) {
        constexpr int SL = decltype(sl_)::v;
        if (IS_FIRST) {
#pragma unroll
            for (int ks = 0; ks < KSx; ks++) {
                rawf[SL][2 * ks + 0] = *(const float4*)(pxf + ks * 32 + 0);
                rawf[SL][2 * ks + 1] = *(const float4*)(pxf + ks * 32 + 4);
            }
            pxf += xstepf;
        } else {
#pragma unroll
            for (int ks = 0; ks < KSx; ks++)
                rawb[SL][ks] = *(const short8*)(pxb + ks * 32);
            pxb += xstepb;
        }
    };

    load_slot(IC<0>{}); load_slot(IC<1>{}); load_slot(IC<2>{}); load_slot(IC<3>{});
    if constexpr (!REGH) __syncthreads();   // hbuf zeros visible

    auto step = [&](auto p_, auto sl_, int s) {
        constexpr int P  = decltype(p_)::v;
        constexpr int SL = decltype(sl_)::v;

        // h B-frags from LDS (issued first; x-MFMAs overlap the lgkm latency)
        short8 fh[KSh];
        if constexpr (!REGH) {
#pragma unroll
            for (int ks = 0; ks < KSh; ks++)
                fh[ks] = *(const short8*)&hbuf[(P * 16 + lm) * HP + ks * 32 + lq * 8];
        }

        // x B-frags from the register ring (packed fp32->bf16 conv on layer 1)
        short8 av[KSx];
        if (IS_FIRST) {
#pragma unroll
            for (int ks = 0; ks < KSx; ks++) {
                union { short8 s; uint_t u[4]; } f;
                const float* ra = (const float*)&rawf[SL][2 * ks];
#pragma unroll
                for (int e = 0; e < 4; e++) f.u[e] = pk_bf16(ra[2 * e], ra[2 * e + 1]);
                av[ks] = f.s;
            }
        } else {
#pragma unroll
            for (int ks = 0; ks < KSx; ks++) av[ks] = rawb[SL][ks];
        }

        floatx4 acc[4][NT];
        // first x-MFMA carries the bias as C (no acc-init movs)
#pragma unroll
        for (int g = 0; g < 4; g++)
#pragma unroll
            for (int t = 0; t < NT; t++)
                acc[g][t] = __builtin_amdgcn_mfma_f32_16x16x32_bf16(aw[g][t][0], av[0], bias4[g][t], 0, 0, 0);
#pragma unroll
        for (int ks = 1; ks < KSx; ks++)
#pragma unroll
            for (int g = 0; g < 4; g++)
#pragma unroll
                for (int t = 0; t < NT; t++)
                    acc[g][t] = __builtin_amdgcn_mfma_f32_16x16x32_bf16(aw[g][t][ks], av[ks], acc[g][t], 0, 0, 0);

        if (s + 4 < T_SEQ) load_slot(sl_);   // refill consumed slot (uniform branch)

        // recurrent part last (shortest possible h -> MFMA distance)
        if constexpr (!REGH) {
#pragma unroll
            for (int ks = 0; ks < KSh; ks++)
#pragma unroll
                for (int g = 0; g < 4; g++)
                    acc[g][0] = __builtin_amdgcn_mfma_f32_16x16x32_bf16(hw[g][0][ks], fh[ks], acc[g][0], 0, 0, 0);
        } else {
#pragma unroll
            for (int c = 0; c < NC; c++)
#pragma unroll
                for (int g = 0; g < 4; g++)
#pragma unroll
                    for (int t = 0; t < NT; t++)
                        acc[g][t] = mfma16(uw[g][t][c], hfrag[c], acc[g][t]);
        }

        // gates + c/h update, pure-register (pre-scaled z; cst = 2log2e*c)
#pragma unroll
        for (int t = 0; t < NT; t++) {
            float hv[4];
#pragma unroll
            for (int r = 0; r < 4; r++) {
                const float gi = rcp_fast(1.0f + exp2_fast(acc[0][t][r]));
                const float gf = rcp_fast(1.0f + exp2_fast(acc[1][t][r]));
                const float gg = 1.0f - 2.0f * rcp_fast(1.0f + exp2_fast(acc[2][t][r]));
                const float go = rcp_fast(1.0f + exp2_fast(acc[3][t][r]));
                cst[t][r] = fmaf(gf, cst[t][r], L2E2 * (gi * gg));
                const float tc = 1.0f - 2.0f * rcp_fast(1.0f + exp2_fast(cst[t][r]));
                hv[r] = go * tc;
            }
            const uint_t d0 = pk_bf16(hv[0], hv[1]);   // units +0,+1
            const uint_t d1 = pk_bf16(hv[2], hv[3]);   // units +2,+3
            if constexpr (REGH) {
                union { uint_t u[2]; short4v s; } pp;
                pp.u[0] = d0; pp.u[1] = d1;
                hfrag[t] = pp.s;                        // next step's h B-frag, in-register
            } else {
                uint2 wv; wv.x = d0; wv.y = d1;
                *(uint2*)&hbuf[((P ^ 1) * 16 + lm) * HP + ug * 16 + lq * 4] = wv;   // 1x b64
            }
            if (SEQ_OUT) {
                uint2 ov; ov.x = d0; ov.y = d1;
                *(uint2*)&pout[t * 16] = ov;            // 1x dwordx2 (was 4x b16)
            } else {
#pragma unroll
                for (int r = 0; r < 4; r++) hl[t][r] = hv[r];
            }
        }
        pout += ostep;
        if (UG > 1) sync_lds();   // lgkm-only; REGH/single-wave layers need no barrier
    };

    for (int s = 0; s < T_SEQ; s += 4) {
        step(IC<0>{}, IC<0>{}, s);
        step(IC<1>{}, IC<1>{}, s + 1);
        step(IC<0>{}, IC<2>{}, s + 2);
        step(IC<1>{}, IC<3>{}, s + 3);
    }

    if (!SEQ_OUT) {
        float* op = (float*)outp;
#pragma unroll
        for (int t = 0; t < NT; t++) {
            float4 v4 = make_float4(hl[t][0], hl[t][1], hl[t][2], hl[t][3]);
            *(float4*)&op[(size_t)(b0 + lm) * (2 * H) + dir * H + (REGH ? t * 16 : ug * 16) + lq * 4] = v4;
        }
    }
}

// Dense head: relu6(x@Wd1+bd1) @ Wd2 + bd2 -> softmax(2). One row per thread.
__global__ __launch_bounds__(256) void dense_head(
    const float* __restrict__ h3, const float* __restrict__ Wd1, const float* __restrict__ bd1,
    const float* __restrict__ Wd2, const float* __restrict__ bd2, float* __restrict__ out)
{
    const int b = blockIdx.x * blockDim.x + threadIdx.x;
    if (b >= BATCH) return;
    float x[32];
#pragma unroll
    for (int k = 0; k < 32; k++) x[k] = h3[b * 32 + k];
    float y[16];
#pragma unroll
    for (int jj = 0; jj < 16; jj++) {
        float a = bd1[jj];
#pragma unroll
        for (int k = 0; k < 32; k++) a = fmaf(x[k], Wd1[k * 16 + jj], a);
        y[jj] = fminf(fmaxf(a, 0.0f), 6.0f);
    }
    float l0 = bd2[0], l1 = bd2[1];
#pragma unroll
    for (int k = 0; k < 16; k++) {
        l0 = fmaf(y[k], Wd2[k * 2 + 0], l0);
        l1 = fmaf(y[k], Wd2[k * 2 + 1], l1);
    }
    const float m = fmaxf(l0, l1);
    const float e0 = __expf(l0 - m), e1 = __expf(l1 - m);
    const float inv = 1.0f / (e0 + e1);
    out[b * 2 + 0] = e0 * inv;
    out[b * 2 + 1] = e1 * inv;
}

extern "C" void kernel_launch(void* const* d_in, const int* in_sizes, int n_in,
                              void* d_out, int out_size, void* d_ws, size_t ws_size,
                              hipStream_t stream)
{
    const float* x   = (const float*)d_in[0];
    const float* W1f = (const float*)d_in[1];
    const float* U1f = (const float*)d_in[2];
    const float* b1f = (const float*)d_in[3];
    const float* W1b = (const float*)d_in[4];
    const float* U1b = (const float*)d_in[5];
    const float* b1b = (const float*)d_in[6];
    const float* W2f = (const float*)d_in[7];
    const float* U2f = (const float*)d_in[8];
    const float* b2f = (const float*)d_in[9];
    const float* W2b = (const float*)d_in[10];
    const float* U2b = (const float*)d_in[11];
    const float* b2b = (const float*)d_in[12];
    const float* W3f = (const float*)d_in[13];
    const float* U3f = (const float*)d_in[14];
    const float* b3f = (const float*)d_in[15];
    const float* W3b = (const float*)d_in[16];
    const float* U3b = (const float*)d_in[17];
    const float* b3b = (const float*)d_in[18];
    const float* Wd1 = (const float*)d_in[19];
    const float* bd1 = (const float*)d_in[20];
    const float* Wd2 = (const float*)d_in[21];
    const float* bd2 = (const float*)d_in[22];

    // workspace: 96 MB + 128 KB footprint
    char* ws = (char*)d_ws;
    void*  l1out = (void*)ws;                                  // [T][B][128] bf16 = 64 MB
    void*  l2out = (void*)(ws + (size_t)64 * 1024 * 1024);     // [T][B][64]  bf16 = 32 MB
    float* h3    = (float*)(ws + (size_t)96 * 1024 * 1024);    // [B][32] fp32 = 128 KB
    float* out   = (float*)d_out;

    dim3 grid(BATCH / 16, 2);

    lstm_fused<64, 64, true, true, false>     // 4 waves/block, LDS h exchange
        <<<grid, 256, 0, stream>>>(x, W1f, U1f, b1f, W1b, U1b, b1b, l1out);
    lstm_fused<128, 32, false, true, false>   // 2 waves/block, LDS h exchange
        <<<grid, 128, 0, stream>>>(l1out, W2f, U2f, b2f, W2b, U2b, b2b, l2out);
    lstm_fused<64, 16, false, false, true>    // 1 wave, register-resident h (fits VGPRs)
        <<<grid, 64, 0, stream>>>(l2out, W3f, U3f, b3f, W3b, U3b, b3b, h3);
    dense_head<<<dim3(BATCH / 256), 256, 0, stream>>>(h3, Wd1, bd1, Wd2, bd2, out);
}

// Round 3
// 506.000 us; speedup vs baseline: 1.2678x; 1.0432x over previous
//
#include <hip/hip_runtime.h>
#include <hip/hip_bf16.h>

#define T_SEQ 256
#define BATCH 1024

typedef __attribute__((ext_vector_type(8))) short  short8;   // 8 bf16 (x32 MFMA frag)
typedef __attribute__((ext_vector_type(4))) short  short4v;  // 4 bf16 (x16 MFMA frag)
typedef __attribute__((ext_vector_type(4))) float  floatx4;  // MFMA C/D frag
typedef unsigned short ushort_t;
typedef unsigned int   uint_t;

template <int P> struct IC { static constexpr int v = P; };

constexpr float NL2E = -1.4426950408889634f;   // -log2(e): sigmoid = rcp(1+exp2(z))
constexpr float L2E2 =  2.8853900817779268f;   // 2*log2(e): tanh = 1-2*rcp(1+exp2(x))

__device__ __forceinline__ float exp2_fast(float x) {
    float r; asm("v_exp_f32 %0, %1" : "=v"(r) : "v"(x)); return r;
}
__device__ __forceinline__ float rcp_fast(float x) {
    float r; asm("v_rcp_f32 %0, %1" : "=v"(r) : "v"(x)); return r;
}
__device__ __forceinline__ ushort_t f2bf(float f) {
    union { float f; uint_t u; } v; v.f = f;
    uint_t r = v.u + 0x7FFFu + ((v.u >> 16) & 1u);   // RNE
    return (ushort_t)(r >> 16);
}
__device__ __forceinline__ uint_t pk_bf16(float a, float b) {
    union { __hip_bfloat162 h; uint_t u; } v;
    v.h = __float22bfloat162_rn(make_float2(a, b));
    return v.u;
}
// Barrier WITHOUT vmcnt drain: LDS ordering only; global loads/stores stay in flight.
__device__ __forceinline__ void sync_lds() {
    asm volatile("s_waitcnt lgkmcnt(0)\n\ts_barrier" ::: "memory");
}

// ============================= MODE ledger (measured) =============================
// MODE 0 = CLASSIC : mfma(A=in, B=w). C: col=unit, row-per-reg. h via LDS (scattered
//                    b16 writes). L1 measured 167.8us (R0).
// MODE 1 = SWAP    : mfma(A=w, B=in). C': lane holds 4 CONSECUTIVE units of one row;
//                    h via LDS (one b64 write / b128 read). L2 measured ~120us (R2).
//                    On L1 this was 200us (R0/R2 A/B) -> NEVER use SWAP for L1.
// MODE 2 = REGH    : SWAP + h in registers via 16x16x16 MFMA. L2: 231us (spills,
//                    R1). L3: ~199us (R1/R2) — WORSE than classic ~170. Retired.
// Weight frags and input loads are byte-identical across modes (A/B maps are the
// same map with m<->n); only mfma operand order, bias index, h-write and output
// addressing differ.
// =================================================================================
__device__ __forceinline__ floatx4 mfma16(short4v a, short4v b, floatx4 c) {
#if __has_builtin(__builtin_amdgcn_mfma_f32_16x16x16bf16_1k)
    return __builtin_amdgcn_mfma_f32_16x16x16bf16_1k(a, b, c, 0, 0, 0);
#else
    floatx4 d;
    asm("v_mfma_f32_16x16x16_bf16 %0, %1, %2, %3" : "=v"(d) : "v"(a), "v"(b), "v"(c));
    return d;
#endif
}

// Fused persistent LSTM layer (one kernel per layer, NO xz materialization).
//  - bias rides as the C operand of the first x-MFMA, hoisted to persistent regs
//    (vs re-init movs every step).
//  - weights pre-scaled (-log2e / 2log2e): all activations are rcp(1+exp2(z));
//    cst holds 2log2e*c to shave one mul off the c->tanh chain.
//  - x frags prefetched 4 steps deep in a register ring (fp32->bf16 packed conv
//    for layer 1); 4-phase unroll => distinct store-data regs, vmcnt looks 4 back.
//  - h ping-pongs in LDS; one lgkm-only barrier per step (none when UG==1).
template <int D, int H, bool IS_FIRST, bool SEQ_OUT, int MODE>
__global__ __launch_bounds__(MODE == 2 ? 64 : 64 * (H / 16), 1) void lstm_fused(
    const void* __restrict__ xin,
    const float* __restrict__ Wf, const float* __restrict__ Uf, const float* __restrict__ bgf,
    const float* __restrict__ Wb, const float* __restrict__ Ub, const float* __restrict__ bgb,
    void* __restrict__ outp)
{
    constexpr bool SW   = (MODE >= 1);           // swapped operand order
    constexpr bool REGH = (MODE == 2);
    constexpr int UG  = REGH ? 1 : H / 16;       // waves per block
    constexpr int NT  = REGH ? H / 16 : 1;       // m-tiles per wave per gate
    constexpr int KSx = D / 32;                  // x k-chunks (16x16x32)
    constexpr int KSh = REGH ? 1 : (H + 31) / 32;// LDS-h k-chunks
    constexpr int NC  = REGH ? H / 16 : 1;       // register-h k-chunks (16x16x16)
    constexpr int HP  = (H < 32 ? 32 : H) + 8;   // padded h row stride (u16)
    constexpr int G4  = 4 * H;
    constexpr int NTH = 64 * UG;
    static_assert(D % 32 == 0 && T_SEQ % 4 == 0, "shape");

    const int tid  = threadIdx.x;
    const int ug   = tid >> 6;
    const int lane = tid & 63;
    const int lm   = lane & 15;
    const int lq   = lane >> 4;
    const int dir  = blockIdx.y;
    const int b0   = blockIdx.x * 16;

    const float* W  = dir ? Wb  : Wf;
    const float* U  = dir ? Ub  : Uf;
    const float* bg = dir ? bgb : bgf;

    __shared__ __align__(16) ushort_t hbuf[REGH ? 8 : 2 * 16 * HP];

    // ---- one-time weight prepack (pre-scaled). Frags identical for all modes. ----
    short8  aw[4][NT][KSx];   // W^T frags
    short8  hw[4][NT][KSh];   // U^T frags (LDS-h path)
    short4v uw[4][NT][NC];    // U^T x16 frags (REGH path; unused otherwise)
    floatx4 bias4[4][NT];     // persistent bias as MFMA C operand
#pragma unroll
    for (int g = 0; g < 4; g++) {
        const float sc = (g == 2) ? L2E2 : NL2E;
#pragma unroll
        for (int t = 0; t < NT; t++) {
            const int ub = g * H + (REGH ? t * 16 : ug * 16);
            floatx4 b4;
#pragma unroll
            for (int r = 0; r < 4; r++)
                b4[r] = sc * bg[ub + (SW ? lq * 4 + r : lm)];   // classic: bcast over rows
            bias4[g][t] = b4;
            const int nc = ub + lm;
#pragma unroll
            for (int ks = 0; ks < KSx; ks++) {
                short8 f;
#pragma unroll
                for (int e = 0; e < 8; e++)
                    f[e] = (short)f2bf(sc * W[(ks * 32 + lq * 8 + e) * G4 + nc]);
                aw[g][t][ks] = f;
            }
            if constexpr (!REGH) {
#pragma unroll
                for (int ks = 0; ks < KSh; ks++) {
                    short8 f;
#pragma unroll
                    for (int e = 0; e < 8; e++) {
                        const int k = ks * 32 + lq * 8 + e;
                        f[e] = (k < H) ? (short)f2bf(sc * U[k * G4 + nc]) : (short)0;
                    }
                    hw[g][t][ks] = f;
                }
            } else {
#pragma unroll
                for (int c = 0; c < NC; c++) {
                    short4v f;
#pragma unroll
                    for (int e = 0; e < 4; e++)
                        f[e] = (short)f2bf(sc * U[(c * 16 + lq * 4 + e) * G4 + nc]);
                    uw[g][t][c] = f;
                }
            }
        }
    }

    if constexpr (!REGH) {
        for (int idx = tid; idx < 2 * 16 * HP; idx += NTH)
            hbuf[idx] = 0;   // h0 = 0; k-padding stays 0 forever
    }

    float   cst[NT][4];      // holds 2log2e * c
    float   hl[NT][4];
    short4v hfrag[NC];       // REGH only
#pragma unroll
    for (int t = 0; t < NT; t++)
#pragma unroll
        for (int r = 0; r < 4; r++) { cst[t][r] = 0.f; hl[t][r] = 0.f; }
    if constexpr (REGH) {
#pragma unroll
        for (int c = 0; c < NC; c++) hfrag[c] = (short4v){0, 0, 0, 0};
    }

    const int t0 = dir ? T_SEQ - 1 : 0;
    // stepping pointers (no per-step 64-bit muls); x loads identical across modes
    const float*    pxf = (const float*)xin + ((size_t)(b0 + lm) * T_SEQ + t0) * D + lq * 8;
    const ushort_t* pxb = (const ushort_t*)xin + ((size_t)t0 * BATCH + b0 + lm) * D + lq * 8;
    const long xstepf = dir ? -(long)D : (long)D;
    const long xstepb = (dir ? -(long)BATCH : (long)BATCH) * D;
    // output pointer, mode-dependent lane->element map
    ushort_t* pout;
    if constexpr (SW)
        pout = (ushort_t*)outp + ((size_t)t0 * BATCH + b0 + lm) * (2 * H) + dir * H +
               (REGH ? 0 : ug * 16) + lq * 4;
    else
        pout = (ushort_t*)outp + ((size_t)t0 * BATCH + b0 + lq * 4) * (2 * H) + dir * H +
               ug * 16 + lm;
    const long ostep = (dir ? -(long)BATCH : (long)BATCH) * (2 * H);

    // x prefetch ring, depth 4
    float4 rawf[4][2 * KSx];   // layer-1 path (fp32 input); DCE'd otherwise
    short8 rawb[4][KSx];       // bf16 path

    auto load_slot = [&](auto sl_) {
        constexpr int SL = decltype(sl_)::v;
        if (IS_FIRST) {
#pragma unroll
            for (int ks = 0; ks < KSx; ks++) {
                rawf[SL][2 * ks + 0] = *(const float4*)(pxf + ks * 32 + 0);
                rawf[SL][2 * ks + 1] = *(const float4*)(pxf + ks * 32 + 4);
            }
            pxf += xstepf;
        } else {
#pragma unroll
            for (int ks = 0; ks < KSx; ks++)
                rawb[SL][ks] = *(const short8*)(pxb + ks * 32);
            pxb += xstepb;
        }
    };

    load_slot(IC<0>{}); load_slot(IC<1>{}); load_slot(IC<2>{}); load_slot(IC<3>{});
    if constexpr (!REGH) __syncthreads();   // hbuf zeros visible

    auto step = [&](auto p_, auto sl_, int s) {
        constexpr int P  = decltype(p_)::v;
        constexpr int SL = decltype(sl_)::v;

        // h frags from LDS (issued first; x-MFMAs overlap the lgkm latency).
        // Same bytes for classic (A-frag) and swap (B-frag).
        short8 fh[KSh];
        if constexpr (!REGH) {
#pragma unroll
            for (int ks = 0; ks < KSh; ks++)
                fh[ks] = *(const short8*)&hbuf[(P * 16 + lm) * HP + ks * 32 + lq * 8];
        }

        // x frags from the register ring (packed fp32->bf16 conv on layer 1)
        short8 av[KSx];
        if (IS_FIRST) {
#pragma unroll
            for (int ks = 0; ks < KSx; ks++) {
                union { short8 s; uint_t u[4]; } f;
                const float* ra = (const float*)&rawf[SL][2 * ks];
#pragma unroll
                for (int e = 0; e < 4; e++) f.u[e] = pk_bf16(ra[2 * e], ra[2 * e + 1]);
                av[ks] = f.s;
            }
        } else {
#pragma unroll
            for (int ks = 0; ks < KSx; ks++) av[ks] = rawb[SL][ks];
        }

        floatx4 acc[4][NT];
        // first x-MFMA carries the (persistent) bias as C — no per-step init movs
#pragma unroll
        for (int g = 0; g < 4; g++)
#pragma unroll
            for (int t = 0; t < NT; t++)
                acc[g][t] = SW
                    ? __builtin_amdgcn_mfma_f32_16x16x32_bf16(aw[g][t][0], av[0], bias4[g][t], 0, 0, 0)
                    : __builtin_amdgcn_mfma_f32_16x16x32_bf16(av[0], aw[g][t][0], bias4[g][t], 0, 0, 0);
#pragma unroll
        for (int ks = 1; ks < KSx; ks++)
#pragma unroll
            for (int g = 0; g < 4; g++)
#pragma unroll
                for (int t = 0; t < NT; t++)
                    acc[g][t] = SW
                        ? __builtin_amdgcn_mfma_f32_16x16x32_bf16(aw[g][t][ks], av[ks], acc[g][t], 0, 0, 0)
                        : __builtin_amdgcn_mfma_f32_16x16x32_bf16(av[ks], aw[g][t][ks], acc[g][t], 0, 0, 0);

        if (s + 4 < T_SEQ) load_slot(sl_);   // refill consumed slot (uniform branch)

        // recurrent part last (shortest possible h -> MFMA distance)
        if constexpr (!REGH) {
#pragma unroll
            for (int ks = 0; ks < KSh; ks++)
#pragma unroll
                for (int g = 0; g < 4; g++)
                    acc[g][0] = SW
                        ? __builtin_amdgcn_mfma_f32_16x16x32_bf16(hw[g][0][ks], fh[ks], acc[g][0], 0, 0, 0)
                        : __builtin_amdgcn_mfma_f32_16x16x32_bf16(fh[ks], hw[g][0][ks], acc[g][0], 0, 0, 0);
        } else {
#pragma unroll
            for (int c = 0; c < NC; c++)
#pragma unroll
                for (int g = 0; g < 4; g++)
#pragma unroll
                    for (int t = 0; t < NT; t++)
                        acc[g][t] = mfma16(uw[g][t][c], hfrag[c], acc[g][t]);
        }

        // gates + c/h update, pure-register (pre-scaled z; cst = 2log2e*c)
#pragma unroll
        for (int t = 0; t < NT; t++) {
            float hv[4];
#pragma unroll
            for (int r = 0; r < 4; r++) {
                const float gi = rcp_fast(1.0f + exp2_fast(acc[0][t][r]));
                const float gf = rcp_fast(1.0f + exp2_fast(acc[1][t][r]));
                const float gg = 1.0f - 2.0f * rcp_fast(1.0f + exp2_fast(acc[2][t][r]));
                const float go = rcp_fast(1.0f + exp2_fast(acc[3][t][r]));
                cst[t][r] = fmaf(gf, cst[t][r], L2E2 * (gi * gg));
                const float tc = 1.0f - 2.0f * rcp_fast(1.0f + exp2_fast(cst[t][r]));
                hv[r] = go * tc;
            }
            if constexpr (SW) {
                const uint_t d0 = pk_bf16(hv[0], hv[1]);   // units +0,+1
                const uint_t d1 = pk_bf16(hv[2], hv[3]);   // units +2,+3
                if constexpr (REGH) {
                    union { uint_t u[2]; short4v s; } pp;
                    pp.u[0] = d0; pp.u[1] = d1;
                    hfrag[t] = pp.s;
                } else {
                    uint2 wv; wv.x = d0; wv.y = d1;
                    *(uint2*)&hbuf[((P ^ 1) * 16 + lm) * HP + ug * 16 + lq * 4] = wv;   // 1x b64
                }
                if (SEQ_OUT) {
                    uint2 ov; ov.x = d0; ov.y = d1;
                    *(uint2*)&pout[t * 16] = ov;            // 1x dwordx2
                } else {
#pragma unroll
                    for (int r = 0; r < 4; r++) hl[t][r] = hv[r];
                }
            } else {
                // classic: lane holds 4 ROWS (lq*4+r) of one unit column (ug*16+lm)
#pragma unroll
                for (int r = 0; r < 4; r++) {
                    const ushort_t hw_ = f2bf(hv[r]);
                    hbuf[((P ^ 1) * 16 + lq * 4 + r) * HP + ug * 16 + lm] = hw_;
                    if (SEQ_OUT) pout[r * 2 * H] = hw_;
                    else         hl[t][r] = hv[r];
                }
            }
        }
        pout += ostep;
        if (UG > 1) sync_lds();   // lgkm-only; single-wave layers need no barrier
    };

    for (int s = 0; s < T_SEQ; s += 4) {
        step(IC<0>{}, IC<0>{}, s);
        step(IC<1>{}, IC<1>{}, s + 1);
        step(IC<0>{}, IC<2>{}, s + 2);
        step(IC<1>{}, IC<3>{}, s + 3);
    }

    if (!SEQ_OUT) {
        float* op = (float*)outp;
        if constexpr (SW) {
#pragma unroll
            for (int t = 0; t < NT; t++) {
                float4 v4 = make_float4(hl[t][0], hl[t][1], hl[t][2], hl[t][3]);
                *(float4*)&op[(size_t)(b0 + lm) * (2 * H) + dir * H +
                              (REGH ? t * 16 : ug * 16) + lq * 4] = v4;
            }
        } else {
#pragma unroll
            for (int r = 0; r < 4; r++)
                op[(size_t)(b0 + lq * 4 + r) * (2 * H) + dir * H + ug * 16 + lm] = hl[0][r];
        }
    }
}

// Dense head: relu6(x@Wd1+bd1) @ Wd2 + bd2 -> softmax(2). One row per thread.
__global__ __launch_bounds__(256) void dense_head(
    const float* __restrict__ h3, const float* __restrict__ Wd1, const float* __restrict__ bd1,
    const float* __restrict__ Wd2, const float* __restrict__ bd2, float* __restrict__ out)
{
    const int b = blockIdx.x * blockDim.x + threadIdx.x;
    if (b >= BATCH) return;
    float x[32];
#pragma unroll
    for (int k = 0; k < 32; k++) x[k] = h3[b * 32 + k];
    float y[16];
#pragma unroll
    for (int jj = 0; jj < 16; jj++) {
        float a = bd1[jj];
#pragma unroll
        for (int k = 0; k < 32; k++) a = fmaf(x[k], Wd1[k * 16 + jj], a);
        y[jj] = fminf(fmaxf(a, 0.0f), 6.0f);
    }
    float l0 = bd2[0], l1 = bd2[1];
#pragma unroll
    for (int k = 0; k < 16; k++) {
        l0 = fmaf(y[k], Wd2[k * 2 + 0], l0);
        l1 = fmaf(y[k], Wd2[k * 2 + 1], l1);
    }
    const float m = fmaxf(l0, l1);
    const float e0 = __expf(l0 - m), e1 = __expf(l1 - m);
    const float inv = 1.0f / (e0 + e1);
    out[b * 2 + 0] = e0 * inv;
    out[b * 2 + 1] = e1 * inv;
}

extern "C" void kernel_launch(void* const* d_in, const int* in_sizes, int n_in,
                              void* d_out, int out_size, void* d_ws, size_t ws_size,
                              hipStream_t stream)
{
    const float* x   = (const float*)d_in[0];
    const float* W1f = (const float*)d_in[1];
    const float* U1f = (const float*)d_in[2];
    const float* b1f = (const float*)d_in[3];
    const float* W1b = (const float*)d_in[4];
    const float* U1b = (const float*)d_in[5];
    const float* b1b = (const float*)d_in[6];
    const float* W2f = (const float*)d_in[7];
    const float* U2f = (const float*)d_in[8];
    const float* b2f = (const float*)d_in[9];
    const float* W2b = (const float*)d_in[10];
    const float* U2b = (const float*)d_in[11];
    const float* b2b = (const float*)d_in[12];
    const float* W3f = (const float*)d_in[13];
    const float* U3f = (const float*)d_in[14];
    const float* b3f = (const float*)d_in[15];
    const float* W3b = (const float*)d_in[16];
    const float* U3b = (const float*)d_in[17];
    const float* b3b = (const float*)d_in[18];
    const float* Wd1 = (const float*)d_in[19];
    const float* bd1 = (const float*)d_in[20];
    const float* Wd2 = (const float*)d_in[21];
    const float* bd2 = (const float*)d_in[22];

    // workspace: 96 MB + 128 KB footprint
    char* ws = (char*)d_ws;
    void*  l1out = (void*)ws;                                  // [T][B][128] bf16 = 64 MB
    void*  l2out = (void*)(ws + (size_t)64 * 1024 * 1024);     // [T][B][64]  bf16 = 32 MB
    float* h3    = (float*)(ws + (size_t)96 * 1024 * 1024);    // [B][32] fp32 = 128 KB
    float* out   = (float*)d_out;

    dim3 grid(BATCH / 16, 2);

    lstm_fused<64, 64, true, true, 0>      // CLASSIC, 4 waves (measured best for L1)
        <<<grid, 256, 0, stream>>>(x, W1f, U1f, b1f, W1b, U1b, b1b, l1out);
    lstm_fused<128, 32, false, true, 1>    // SWAP-LDS, 2 waves (measured best for L2)
        <<<grid, 128, 0, stream>>>(l1out, W2f, U2f, b2f, W2b, U2b, b2b, l2out);
    lstm_fused<64, 16, false, false, 1>    // SWAP-LDS, 1 wave, barrier-free
        <<<grid, 64, 0, stream>>>(l2out, W3f, U3f, b3f, W3b, U3b, b3b, h3);
    dense_head<<<dim3(BATCH / 256), 256, 0, stream>>>(h3, Wd1, bd1, Wd2, bd2, out);
}